// Round 2
// baseline (179.843 us; speedup 1.0000x reference)
//
#include <hip/hip_runtime.h>
#include <cstdint>

#define PERB 262144   // C*H*H = N*D elements per batch

typedef __attribute__((ext_vector_type(8))) short bf16x8;
typedef __attribute__((ext_vector_type(4))) float f32x4;
typedef unsigned short ushort_t;

__device__ __forceinline__ uint16_t f2bf(float f) {
    uint32_t u = __float_as_uint(f);
    u += 0x7fff + ((u >> 16) & 1);   // RNE
    return (uint16_t)(u >> 16);
}

// ---------------------------------------------------------------------------
// Kernel 0: fused prep.
//   blocks [0,256)   : convert the 4 weight matrices (256x256 fp32) to bf16
//   blocks [256,768) : LayerNorm over channel axis -> bf16 X
// ---------------------------------------------------------------------------
__global__ __launch_bounds__(256) void prep_kernel(
    const float* __restrict__ x, const float* __restrict__ gam,
    const float* __restrict__ bet, ushort_t* __restrict__ X,
    const float* __restrict__ wq, const float* __restrict__ wk,
    const float* __restrict__ wv, const float* __restrict__ wo,
    ushort_t* __restrict__ oq, ushort_t* __restrict__ ok,
    ushort_t* __restrict__ ov, ushort_t* __restrict__ oo)
{
    const int blk = blockIdx.x;
    const int tid = threadIdx.x;
    if (blk < 256) {
        const int which = blk >> 6;
        const int idx = ((blk & 63) * 256 + tid) * 4;
        const float* src = which == 0 ? wq : which == 1 ? wk : which == 2 ? wv : wo;
        ushort_t* dst    = which == 0 ? oq : which == 1 ? ok : which == 2 ? ov : oo;
        const float4 v = *(const float4*)&src[idx];
        uint2 p;
        p.x = (uint32_t)f2bf(v.x) | ((uint32_t)f2bf(v.y) << 16);
        p.y = (uint32_t)f2bf(v.z) | ((uint32_t)f2bf(v.w) << 16);
        *(uint2*)&dst[idx] = p;
        return;
    }
    const int lb  = blk - 256;            // 512 blocks
    const int b   = lb >> 5;
    const int sp0 = (lb & 31) << 5;
    const int spl = tid & 31;
    const int cg  = tid >> 5;
    const int c0  = cg << 5;
    const int sp  = sp0 + spl;
    const float* xb = x + (size_t)b * PERB + sp;

    float vals[32];
    float s = 0.f, sq = 0.f;
#pragma unroll
    for (int i = 0; i < 32; ++i) {
        float v = xb[(size_t)(c0 + i) * 1024];
        vals[i] = v; s += v; sq += v * v;
    }
    __shared__ float rs[8][32];
    __shared__ float rq[8][32];
    rs[cg][spl] = s; rq[cg][spl] = sq;
    __syncthreads();
    float ts = 0.f, tq = 0.f;
#pragma unroll
    for (int g = 0; g < 8; ++g) { ts += rs[g][spl]; tq += rq[g][spl]; }
    const float mean = ts * (1.f / 256.f);
    const float var  = tq * (1.f / 256.f) - mean * mean;
    const float rstd = rsqrtf(var + 1e-5f);

    ushort_t* Xb = X + (size_t)b * PERB + sp;
#pragma unroll
    for (int i = 0; i < 32; ++i) {
        const int cc = c0 + i;
        Xb[(size_t)cc * 1024] = f2bf((vals[i] - mean) * rstd * gam[cc] + bet[cc]);
    }
}

// ---------------------------------------------------------------------------
// Kernel 2: MFMA fused Q/K/V projection.
//  Round-9 change: Q and K are written in TOKEN-MAJOR layout
//  (QT/KT flat = b*262144 + h*32768 + tok*32 + s) so attn can stage them with
//  vectorized bf16x8 loads instead of stride-1024 u16 gathers. V unchanged.
// ---------------------------------------------------------------------------
__global__ __launch_bounds__(256, 3) void qkv_kernel(
    const ushort_t* __restrict__ X,
    const ushort_t* __restrict__ wq, const float* __restrict__ bq,
    const ushort_t* __restrict__ wk, const float* __restrict__ bk,
    const ushort_t* __restrict__ wv, const float* __restrict__ bv,
    ushort_t* __restrict__ QT, ushort_t* __restrict__ KT, ushort_t* __restrict__ V)
{
    __shared__ __align__(16) ushort_t Xl[512 * 8];
    __shared__ __align__(16) ushort_t Wl[3][512 * 8];

    const int blk = blockIdx.x;
    const int m0  = (blk >> 2) << 6;
    const int n0  = (blk & 3) << 6;
    const int tid = threadIdx.x;
    const int w    = tid >> 6;
    const int lane = tid & 63;
    const int quad = lane >> 4;
    const int c    = lane & 15;

    f32x4 acc[3][4];
#pragma unroll
    for (int o3 = 0; o3 < 3; ++o3)
#pragma unroll
        for (int i = 0; i < 4; ++i) acc[o3][i] = (f32x4){0.f, 0.f, 0.f, 0.f};

    for (int kc = 0; kc < 4; ++kc) {
        const int k0 = kc << 6;
        __syncthreads();
#pragma unroll
        for (int i = 0; i < 2; ++i) {
            const int id = tid + i * 256;
            const int kq = id >> 6, m = id & 63;
            *(bf16x8*)&Xl[id * 8] = *(const bf16x8*)&X[(size_t)(m0 + m) * 256 + k0 + kq * 8];
        }
#pragma unroll
        for (int i = 0; i < 2; ++i) {
            const int id = tid + i * 256;
            const int kq = id >> 6, n = id & 63;
            const size_t g = (size_t)(n0 + n) * 256 + k0 + kq * 8;
            *(bf16x8*)&Wl[0][id * 8] = *(const bf16x8*)&wq[g];
            *(bf16x8*)&Wl[1][id * 8] = *(const bf16x8*)&wk[g];
            *(bf16x8*)&Wl[2][id * 8] = *(const bf16x8*)&wv[g];
        }
        __syncthreads();
#pragma unroll
        for (int ks = 0; ks < 2; ++ks) {
            const int kq = ks * 4 + quad;
            bf16x8 af[4];
#pragma unroll
            for (int msub = 0; msub < 4; ++msub)
                af[msub] = *(const bf16x8*)&Xl[(kq * 64 + msub * 16 + c) * 8];
            bf16x8 bw[3];
#pragma unroll
            for (int o3 = 0; o3 < 3; ++o3)
                bw[o3] = *(const bf16x8*)&Wl[o3][(kq * 64 + w * 16 + c) * 8];
#pragma unroll
            for (int o3 = 0; o3 < 3; ++o3)
#pragma unroll
                for (int msub = 0; msub < 4; ++msub)
                    acc[o3][msub] = __builtin_amdgcn_mfma_f32_16x16x32_bf16(
                        bw[o3], af[msub], acc[o3][msub], 0, 0, 0);
        }
    }

    const int n = n0 + w * 16 + quad * 4;
    const float4 bq4 = *(const float4*)&bq[n];
    const float4 bk4 = *(const float4*)&bk[n];
    const float4 bv4 = *(const float4*)&bv[n];
    const float bqa[4] = {bq4.x, bq4.y, bq4.z, bq4.w};
    const float bka[4] = {bk4.x, bk4.y, bk4.z, bk4.w};
#pragma unroll
    for (int msub = 0; msub < 4; ++msub) {
        const int m = m0 + msub * 16 + c;      // global token row 0..16383
        // --- V: vector write (layout unchanged) ---
        const f32x4 av = acc[2][msub];
        uint2 pv;
        pv.x = (uint32_t)f2bf(av[0] + bv4.x) | ((uint32_t)f2bf(av[1] + bv4.y) << 16);
        pv.y = (uint32_t)f2bf(av[2] + bv4.z) | ((uint32_t)f2bf(av[3] + bv4.w) << 16);
        *(uint2*)&V[(size_t)m * 256 + n] = pv;
        // --- Q/K: scatter to token-major [b][h][tok][s] ---
        // flat-in-batch = tw*256 + feat ; h = tw>>7 ; s = (tw>>2)&31 ;
        // tok = (tw&3)*256 + feat
        const int tw = m & 1023;
        const size_t tb = (size_t)(m >> 10) * 262144
                        + (size_t)(tw >> 7) * 32768 + (size_t)((tw >> 2) & 31);
        const int ta = (tw & 3) * 256 + n;
#pragma unroll
        for (int r = 0; r < 4; ++r) {
            QT[tb + (size_t)(ta + r) * 32] = f2bf(acc[0][msub][r] + bqa[r]);
            KT[tb + (size_t)(ta + r) * 32] = f2bf(acc[1][msub][r] + bka[r]);
        }
    }
}

// ---------------------------------------------------------------------------
// Kernel 3: MFMA flash attention, round-9.
//  Counters showed latency-bound (MfmaUtil 17, VALUBusy 51, no pipe >60%),
//  invariant to occupancy knobs -> attack the per-chunk critical path:
//   * n-chunk 64 -> 128: halves barriers (32 -> 16/block), 2x MFMA per phase
//   * K/Q staged from token-major QT/KT: 2 bf16x8 loads vs 16 scalar gathers
//   * bias loads hoisted to top of S phase (latency hides under 8 MFMAs)
//   * s_setprio(1) around MFMA clusters (T5)
// ---------------------------------------------------------------------------
#define C1F 0.09016844005556022f   // 0.0625 * log2(e)
#define LOG2EF 1.4426950408889634f

__global__ __launch_bounds__(256, 3) void attn_kernel(
    const ushort_t* __restrict__ QT, const ushort_t* __restrict__ KT,
    const ushort_t* __restrict__ V, const float* __restrict__ relb,
    ushort_t* __restrict__ O)
{
    // LDS map (bytes):
    //   [0, 16384)       P: 64 rows x 256B (16 units of 16B, unit ^= row&15);
    //                    Q staging at start (first 4KB)
    //   [16384, 24576)   K: granule (s>>3)*2048 + tok*16
    //   [24576, 40960)   V dbuf: buf*8192 + d*256, unit ^= d&15
    __shared__ __align__(16) unsigned char smem[40960];
    char* Pb = (char*)smem;
    char* Kl = (char*)(smem + 16384);
    char* Vl = (char*)(smem + 24576);

    const int blk = blockIdx.x;
    const int bh  = blk & 127;
    const int mt  = blk >> 7;            // 16 m-tiles of 64
    const int b   = bh >> 3;
    const int h   = bh & 7;
    const int m0  = mt << 6;
    const int tid = threadIdx.x;
    const int w    = tid >> 6;
    const int lane = tid & 63;
    const int quad = lane >> 4;
    const int c    = lane & 15;

    const size_t base = (size_t)b * PERB + (size_t)h * 32768;
    const ushort_t* QTg = QT + base;
    const ushort_t* KTg = KT + base;
    const ushort_t* Vg  = V + base;
    const float* rbh = relb + h * 3969;

    // ---- stage Q [64m x 32s] from token-major QT: one bf16x8 per thread ----
    {
        const int mm = tid & 63;
        const int sg = tid >> 6;         // s-group of 8
        const bf16x8 qv = *(const bf16x8*)&QTg[(size_t)(m0 + mm) * 32 + sg * 8];
        *(bf16x8*)(Pb + sg * 1024 + mm * 16) = qv;
    }
    __syncthreads();
    bf16x8 qfrag[4];
#pragma unroll
    for (int msub = 0; msub < 4; ++msub)
        qfrag[msub] = *(const bf16x8*)(Pb + quad * 1024 + (msub * 16 + c) * 16);

    int moff[4];
#pragma unroll
    for (int msub = 0; msub < 4; ++msub) {
        const int m = m0 + msub * 16 + c;
        moff[msub] = 1984 - (m >> 5) * 63 - (m & 31);
    }

    f32x4 oacc[2], dacc;
    dacc = (f32x4){0.f, 0.f, 0.f, 0.f};
#pragma unroll
    for (int j = 0; j < 2; ++j) oacc[j] = (f32x4){0.f, 0.f, 0.f, 0.f};
    bf16x8 onesf;
#pragma unroll
    for (int j = 0; j < 8; ++j) onesf[j] = (short)0x3F80;

    // staging thread coords + hoisted LDS addresses
    const int knn = tid & 63, ksg = tid >> 6;   // K: sgroup ksg, tokens knn/knn+64
    const int vs  = tid >> 3, vng = tid & 7;    // V: d-row vs, units vng/vng+8
    const int kWr  = ksg * 2048 + knn * 16;
    const int vWr0 = vs * 256 + ((vng ^ (vs & 15)) << 4);
    const int vWr1 = vs * 256 + (((vng + 8) ^ (vs & 15)) << 4);
    const int kRd0 = quad * 2048 + (w * 32 + c) * 16;        // nsub 0
    const int kRd1 = quad * 2048 + (w * 32 + 16 + c) * 16;   // nsub 1

    // prologue: prefetch chunk 0 (all vectorized now)
    bf16x8 kpre0, kpre1, vpre0, vpre1;
    kpre0 = *(const bf16x8*)&KTg[(size_t)knn * 32 + ksg * 8];
    kpre1 = *(const bf16x8*)&KTg[(size_t)(64 + knn) * 32 + ksg * 8];
    vpre0 = *(const bf16x8*)&Vg[(size_t)vs * 1024 + vng * 8];
    vpre1 = *(const bf16x8*)&Vg[(size_t)vs * 1024 + 64 + vng * 8];

    for (int ch = 0; ch < 8; ++ch) {
        const int n0c = ch << 7;
        const int cb  = ch & 1;

        // ---- write prefetched K/V to LDS ----
        *(bf16x8*)(Kl + kWr)        = kpre0;
        *(bf16x8*)(Kl + kWr + 1024) = kpre1;
        *(bf16x8*)(Vl + cb * 8192 + vWr0) = vpre0;
        *(bf16x8*)(Vl + cb * 8192 + vWr1) = vpre1;
        __syncthreads();   // staging visible; prev PV done for all waves

        // ---- bias loads for THIS chunk (L1-hot; hides under S MFMAs) ----
        float bb[4][2][4];
#pragma unroll
        for (int nsub = 0; nsub < 2; ++nsub) {
            const int nbase = n0c + w * 32 + nsub * 16 + quad * 4;
            const int nidx = (nbase >> 5) * 63 + (nbase & 31);
#pragma unroll
            for (int msub = 0; msub < 4; ++msub) {
                const float* bp = rbh + nidx + moff[msub];
#pragma unroll
                for (int r = 0; r < 4; ++r) bb[msub][nsub][r] = bp[r];
            }
        }

        // ---- prefetch next chunk into regs (overlaps S + exp) ----
        {
            const int n0n = ((ch + 1) & 7) << 7;
            kpre0 = *(const bf16x8*)&KTg[(size_t)(n0n + knn) * 32 + ksg * 8];
            kpre1 = *(const bf16x8*)&KTg[(size_t)(n0n + 64 + knn) * 32 + ksg * 8];
            vpre0 = *(const bf16x8*)&Vg[(size_t)vs * 1024 + n0n + vng * 8];
            vpre1 = *(const bf16x8*)&Vg[(size_t)vs * 1024 + n0n + 64 + vng * 8];
        }

        // ---- S phase: 8 MFMA ----
        const bf16x8 kf0 = *(const bf16x8*)(Kl + kRd0);
        const bf16x8 kf1 = *(const bf16x8*)(Kl + kRd1);
        f32x4 sacc[4][2];
        __builtin_amdgcn_s_setprio(1);
#pragma unroll
        for (int msub = 0; msub < 4; ++msub) {
            const f32x4 z = {0.f, 0.f, 0.f, 0.f};
            sacc[msub][0] = __builtin_amdgcn_mfma_f32_16x16x32_bf16(kf0, qfrag[msub], z, 0, 0, 0);
            sacc[msub][1] = __builtin_amdgcn_mfma_f32_16x16x32_bf16(kf1, qfrag[msub], z, 0, 0, 0);
        }
        __builtin_amdgcn_s_setprio(0);

        // ---- exp2 + trunc-pack + P write ----
#pragma unroll
        for (int msub = 0; msub < 4; ++msub) {
#pragma unroll
            for (int nsub = 0; nsub < 2; ++nsub) {
                float p[4];
#pragma unroll
                for (int r = 0; r < 4; ++r)
                    p[r] = __builtin_amdgcn_exp2f(
                        fmaf(bb[msub][nsub][r], LOG2EF, sacc[msub][nsub][r] * C1F));
                uint2 pk;
                pk.x = __builtin_amdgcn_perm(__float_as_uint(p[1]), __float_as_uint(p[0]), 0x07060302u);
                pk.y = __builtin_amdgcn_perm(__float_as_uint(p[3]), __float_as_uint(p[2]), 0x07060302u);
                const int pWr = (msub * 16 + c) * 256
                              + (((4 * w + 2 * nsub + (quad >> 1)) ^ c) << 4)
                              + ((quad & 1) << 3);
                *(uint2*)(Pb + pWr) = pk;
            }
        }
        __syncthreads();   // P (and V) ready for PV

        // ---- PV phase: wave w owns m-rows [w*16, w*16+16) ----
        const char* Vc = Vl + cb * 8192;
        __builtin_amdgcn_s_setprio(1);
#pragma unroll
        for (int kstep = 0; kstep < 4; ++kstep) {
            const int uu = ((kstep * 4 + quad) ^ c) << 4;
            const bf16x8 vf0 = *(const bf16x8*)(Vc + c * 256 + uu);
            const bf16x8 vf1 = *(const bf16x8*)(Vc + (16 + c) * 256 + uu);
            const bf16x8 pf  = *(const bf16x8*)(Pb + (w * 16 + c) * 256 + uu);
            oacc[0] = __builtin_amdgcn_mfma_f32_16x16x32_bf16(vf0, pf, oacc[0], 0, 0, 0);
            oacc[1] = __builtin_amdgcn_mfma_f32_16x16x32_bf16(vf1, pf, oacc[1], 0, 0, 0);
            dacc    = __builtin_amdgcn_mfma_f32_16x16x32_bf16(onesf, pf, dacc, 0, 0, 0);
        }
        __builtin_amdgcn_s_setprio(0);
    }

    // ---- epilogue: scale by 1/denominator, write O ----
    ushort_t* Ob = O + base;
    const float inv = 1.0f / dacc[0];
    const int m = m0 + w * 16 + c;
#pragma unroll
    for (int ssub = 0; ssub < 2; ++ssub)
#pragma unroll
        for (int r = 0; r < 4; ++r)
            Ob[(size_t)(ssub * 16 + quad * 4 + r) * 1024 + m] = f2bf(oacc[ssub][r] * inv);
}

// ---------------------------------------------------------------------------
// Kernel 4: MFMA output projection + bias + residual. Unchanged.
// ---------------------------------------------------------------------------
__global__ __launch_bounds__(256, 4) void oproj_kernel(
    const ushort_t* __restrict__ A, const ushort_t* __restrict__ wo,
    const float* __restrict__ bo, const float* __restrict__ x,
    float* __restrict__ out)
{
    __shared__ __align__(16) ushort_t Al[512 * 8];
    __shared__ __align__(16) ushort_t Wl[512 * 8];

    const int blk = blockIdx.x;
    const int m0  = (blk >> 2) << 6;
    const int n0  = (blk & 3) << 6;
    const int tid = threadIdx.x;
    const int w    = tid >> 6;
    const int lane = tid & 63;
    const int quad = lane >> 4;
    const int c    = lane & 15;

    f32x4 acc[4];
#pragma unroll
    for (int i = 0; i < 4; ++i) acc[i] = (f32x4){0.f, 0.f, 0.f, 0.f};

    for (int kc = 0; kc < 4; ++kc) {
        const int k0 = kc << 6;
        __syncthreads();
#pragma unroll
        for (int i = 0; i < 2; ++i) {
            const int id = tid + i * 256;
            const int kq = id >> 6, mn = id & 63;
            *(bf16x8*)&Al[id * 8] = *(const bf16x8*)&A [(size_t)(m0 + mn) * 256 + k0 + kq * 8];
            *(bf16x8*)&Wl[id * 8] = *(const bf16x8*)&wo[(size_t)(n0 + mn) * 256 + k0 + kq * 8];
        }
        __syncthreads();
#pragma unroll
        for (int ks = 0; ks < 2; ++ks) {
            const int kq = ks * 4 + quad;
            const bf16x8 bw = *(const bf16x8*)&Wl[(kq * 64 + w * 16 + c) * 8];
#pragma unroll
            for (int msub = 0; msub < 4; ++msub) {
                const bf16x8 af = *(const bf16x8*)&Al[(kq * 64 + msub * 16 + c) * 8];
                acc[msub] = __builtin_amdgcn_mfma_f32_16x16x32_bf16(bw, af, acc[msub], 0, 0, 0);
            }
        }
    }

    const int n = n0 + w * 16 + quad * 4;
    const float4 bo4 = *(const float4*)&bo[n];
#pragma unroll
    for (int msub = 0; msub < 4; ++msub) {
        const size_t g = (size_t)(m0 + msub * 16 + c) * 256 + n;
        const float4 r = *(const float4*)&x[g];
        float4 t;
        t.x = acc[msub][0] + bo4.x + r.x;
        t.y = acc[msub][1] + bo4.y + r.y;
        t.z = acc[msub][2] + bo4.z + r.z;
        t.w = acc[msub][3] + bo4.w + r.w;
        *(float4*)&out[g] = t;
    }
}

// ---------------------------------------------------------------------------
extern "C" void kernel_launch(void* const* d_in, const int* in_sizes, int n_in,
                              void* d_out, int out_size, void* d_ws, size_t ws_size,
                              hipStream_t stream)
{
    (void)in_sizes; (void)n_in; (void)out_size; (void)ws_size;
    const float* x   = (const float*)d_in[0];
    const float* lng = (const float*)d_in[1];
    const float* lnb = (const float*)d_in[2];
    const float* wq  = (const float*)d_in[3];
    const float* bq  = (const float*)d_in[4];
    const float* wk  = (const float*)d_in[5];
    const float* bk  = (const float*)d_in[6];
    const float* wv  = (const float*)d_in[7];
    const float* bv  = (const float*)d_in[8];
    const float* wo  = (const float*)d_in[9];
    const float* bo  = (const float*)d_in[10];
    const float* rb  = (const float*)d_in[11];
    // d_in[12] (rel_idx) unused: index recomputed analytically in-kernel.

    ushort_t* ws = (ushort_t*)d_ws;
    ushort_t* Xbf = ws;                       // 4194304 elems each
    ushort_t* Qbf = ws + 1 * 4194304;         // holds QT (token-major)
    ushort_t* Kbf = ws + 2 * 4194304;         // holds KT (token-major)
    ushort_t* Vbf = ws + 3 * 4194304;
    ushort_t* Obf = ws + 4 * 4194304;
    ushort_t* Wqb = ws + 5 * 4194304;
    ushort_t* Wkb = Wqb + 65536;
    ushort_t* Wvb = Wkb + 65536;
    ushort_t* Wob = Wvb + 65536;
    float* out = (float*)d_out;

    hipLaunchKernelGGL(prep_kernel,  dim3(768),  dim3(256), 0, stream,
                       x, lng, lnb, Xbf, wq, wk, wv, wo, Wqb, Wkb, Wvb, Wob);
    hipLaunchKernelGGL(qkv_kernel,   dim3(1024), dim3(256), 0, stream,
                       Xbf, Wqb, bq, Wkb, bk, Wvb, bv, Qbf, Kbf, Vbf);
    hipLaunchKernelGGL(attn_kernel,  dim3(2048), dim3(256), 0, stream, Qbf, Kbf, Vbf, rb, Obf);
    hipLaunchKernelGGL(oproj_kernel, dim3(1024), dim3(256), 0, stream, Obf, Wob, bo, x, out);
}

// Round 3
// 161.201 us; speedup vs baseline: 1.1156x; 1.1156x over previous
//
#include <hip/hip_runtime.h>
#include <cstdint>

#define PERB 262144   // C*H*H = N*D elements per batch

typedef __attribute__((ext_vector_type(8))) short bf16x8;
typedef __attribute__((ext_vector_type(4))) float f32x4;
typedef unsigned short ushort_t;

__device__ __forceinline__ uint16_t f2bf(float f) {
    uint32_t u = __float_as_uint(f);
    u += 0x7fff + ((u >> 16) & 1);   // RNE
    return (uint16_t)(u >> 16);
}

// async global->LDS, 16B per lane. LDS dest is wave-uniform base (+lane*16 by HW);
// global src is per-lane.
__device__ __forceinline__ void glds16(const void* g, void* l) {
    __builtin_amdgcn_global_load_lds(
        (const __attribute__((address_space(1))) void*)g,
        (__attribute__((address_space(3))) void*)l, 16, 0, 0);
}

// ---------------------------------------------------------------------------
// Kernel 0: fused prep.
//   blocks [0,256)   : convert the 4 weight matrices (256x256 fp32) to bf16
//   blocks [256,768) : LayerNorm over channel axis -> bf16 X
// ---------------------------------------------------------------------------
__global__ __launch_bounds__(256) void prep_kernel(
    const float* __restrict__ x, const float* __restrict__ gam,
    const float* __restrict__ bet, ushort_t* __restrict__ X,
    const float* __restrict__ wq, const float* __restrict__ wk,
    const float* __restrict__ wv, const float* __restrict__ wo,
    ushort_t* __restrict__ oq, ushort_t* __restrict__ ok,
    ushort_t* __restrict__ ov, ushort_t* __restrict__ oo)
{
    const int blk = blockIdx.x;
    const int tid = threadIdx.x;
    if (blk < 256) {
        const int which = blk >> 6;
        const int idx = ((blk & 63) * 256 + tid) * 4;
        const float* src = which == 0 ? wq : which == 1 ? wk : which == 2 ? wv : wo;
        ushort_t* dst    = which == 0 ? oq : which == 1 ? ok : which == 2 ? ov : oo;
        const float4 v = *(const float4*)&src[idx];
        uint2 p;
        p.x = (uint32_t)f2bf(v.x) | ((uint32_t)f2bf(v.y) << 16);
        p.y = (uint32_t)f2bf(v.z) | ((uint32_t)f2bf(v.w) << 16);
        *(uint2*)&dst[idx] = p;
        return;
    }
    const int lb  = blk - 256;            // 512 blocks
    const int b   = lb >> 5;
    const int sp0 = (lb & 31) << 5;
    const int spl = tid & 31;
    const int cg  = tid >> 5;
    const int c0  = cg << 5;
    const int sp  = sp0 + spl;
    const float* xb = x + (size_t)b * PERB + sp;

    float vals[32];
    float s = 0.f, sq = 0.f;
#pragma unroll
    for (int i = 0; i < 32; ++i) {
        float v = xb[(size_t)(c0 + i) * 1024];
        vals[i] = v; s += v; sq += v * v;
    }
    __shared__ float rs[8][32];
    __shared__ float rq[8][32];
    rs[cg][spl] = s; rq[cg][spl] = sq;
    __syncthreads();
    float ts = 0.f, tq = 0.f;
#pragma unroll
    for (int g = 0; g < 8; ++g) { ts += rs[g][spl]; tq += rq[g][spl]; }
    const float mean = ts * (1.f / 256.f);
    const float var  = tq * (1.f / 256.f) - mean * mean;
    const float rstd = rsqrtf(var + 1e-5f);

    ushort_t* Xb = X + (size_t)b * PERB + sp;
#pragma unroll
    for (int i = 0; i < 32; ++i) {
        const int cc = c0 + i;
        Xb[(size_t)cc * 1024] = f2bf((vals[i] - mean) * rstd * gam[cc] + bet[cc]);
    }
}

// ---------------------------------------------------------------------------
// Kernel 2: MFMA fused Q/K/V projection, round-10 rebuild.
//  Round-2 counters exposed qkv at 49us with MfmaUtil 4.4%/VALUBusy 4.5%:
//  the staging loads (64 lanes x 512B stride) were 64-line TA gathers and the
//  reg-roundtrip staging serialized on L2 latency every kc.
//  Fix: (a) 8-lanes-per-row loads -> 8x128B contiguous segments per load;
//       (b) global_load_lds 16B direct-to-LDS (no reg roundtrip, no VALU);
//       (c) XOR-swizzle (koct = u ^ row&7) applied on the GLOBAL src so the
//           linear LDS dest gives conflict-free ds_read_b128 (2-way = free);
//       (d) double-buffer in two distinct __shared__ objects, stage(kc+1)
//           issued before compute(kc), one __syncthreads per kc.
//  Epilogue reverted to feature-major uint2 stores (round-1 form).
// ---------------------------------------------------------------------------
__device__ __forceinline__ void qkv_stage(
    ushort_t* Sb, const ushort_t* __restrict__ X,
    const ushort_t* __restrict__ wq, const ushort_t* __restrict__ wk,
    const ushort_t* __restrict__ wv,
    int m0, int n0, int k0, int w, int lane)
{
    const int rsub = lane >> 3;          // 0..7  row-within-8-group
    const int u    = lane & 7;           // 16B unit within 128B row
    const int koct = u ^ rsub;           // pre-swizzled global k-octet
#pragma unroll
    for (int i = 0; i < 2; ++i) {
        const int rg  = w * 2 + i;       // 8-row group 0..7
        const int row = rg * 8 + rsub;   // row&7 == rsub
        const int go  = k0 + koct * 8;
        ushort_t* db = Sb + rg * 512;    // wave-uniform dest base (+lane*16B by HW)
        glds16(&X [(size_t)(m0 + row) * 256 + go], db);
        glds16(&wq[(size_t)(n0 + row) * 256 + go], db + 4096);
        glds16(&wk[(size_t)(n0 + row) * 256 + go], db + 8192);
        glds16(&wv[(size_t)(n0 + row) * 256 + go], db + 12288);
    }
}

__device__ __forceinline__ void qkv_compute(
    const ushort_t* Sb, int w, int c, int quad, f32x4 acc[3][4])
{
#pragma unroll
    for (int ks = 0; ks < 2; ++ks) {
        const int kq = ks * 4 + quad;
        const int uo = (kq ^ (c & 7)) * 8;
        bf16x8 af[4];
#pragma unroll
        for (int msub = 0; msub < 4; ++msub)
            af[msub] = *(const bf16x8*)&Sb[(msub * 16 + c) * 64 + uo];
        bf16x8 bw[3];
#pragma unroll
        for (int o3 = 0; o3 < 3; ++o3)
            bw[o3] = *(const bf16x8*)&Sb[(o3 + 1) * 4096 + (w * 16 + c) * 64 + uo];
#pragma unroll
        for (int o3 = 0; o3 < 3; ++o3)
#pragma unroll
            for (int msub = 0; msub < 4; ++msub)
                acc[o3][msub] = __builtin_amdgcn_mfma_f32_16x16x32_bf16(
                    bw[o3], af[msub], acc[o3][msub], 0, 0, 0);
    }
}

__global__ __launch_bounds__(256) void qkv_kernel(
    const ushort_t* __restrict__ X,
    const ushort_t* __restrict__ wq, const float* __restrict__ bq,
    const ushort_t* __restrict__ wk, const float* __restrict__ bk,
    const ushort_t* __restrict__ wv, const float* __restrict__ bv,
    ushort_t* __restrict__ Q, ushort_t* __restrict__ K, ushort_t* __restrict__ V)
{
    // two distinct LDS objects -> alias analysis keeps glds(buf^1) independent
    // of ds_read(buf); panels: [0]=X, [1]=Wq, [2]=Wk, [3]=Wv, each 64x64 bf16.
    __shared__ __align__(16) ushort_t SB0[4][4096];
    __shared__ __align__(16) ushort_t SB1[4][4096];

    const int blk = blockIdx.x;
    const int m0  = (blk >> 2) << 6;
    const int n0  = (blk & 3) << 6;
    const int tid = threadIdx.x;
    const int w    = tid >> 6;
    const int lane = tid & 63;
    const int quad = lane >> 4;
    const int c    = lane & 15;

    f32x4 acc[3][4];
#pragma unroll
    for (int o3 = 0; o3 < 3; ++o3)
#pragma unroll
        for (int i = 0; i < 4; ++i) acc[o3][i] = (f32x4){0.f, 0.f, 0.f, 0.f};

    qkv_stage(&SB0[0][0], X, wq, wk, wv, m0, n0, 0, w, lane);
    __syncthreads();
#pragma unroll
    for (int kc = 0; kc < 4; ++kc) {
        if (kc < 3) {
            if ((kc & 1) == 0)
                qkv_stage(&SB1[0][0], X, wq, wk, wv, m0, n0, (kc + 1) << 6, w, lane);
            else
                qkv_stage(&SB0[0][0], X, wq, wk, wv, m0, n0, (kc + 1) << 6, w, lane);
        }
        if ((kc & 1) == 0) qkv_compute(&SB0[0][0], w, c, quad, acc);
        else               qkv_compute(&SB1[0][0], w, c, quad, acc);
        __syncthreads();   // drains in-flight glds (overlapped with compute) + barrier
    }

    const int n = n0 + w * 16 + quad * 4;
    const float4 bq4 = *(const float4*)&bq[n];
    const float4 bk4 = *(const float4*)&bk[n];
    const float4 bv4 = *(const float4*)&bv[n];
    ushort_t* outs[3] = {Q, K, V};
    const float4 bias[3] = {bq4, bk4, bv4};
#pragma unroll
    for (int msub = 0; msub < 4; ++msub) {
        const size_t m = (size_t)(m0 + msub * 16 + c);
#pragma unroll
        for (int o3 = 0; o3 < 3; ++o3) {
            const f32x4 a = acc[o3][msub];
            uint2 p;
            p.x = (uint32_t)f2bf(a[0] + bias[o3].x) | ((uint32_t)f2bf(a[1] + bias[o3].y) << 16);
            p.y = (uint32_t)f2bf(a[2] + bias[o3].z) | ((uint32_t)f2bf(a[3] + bias[o3].w) << 16);
            *(uint2*)&outs[o3][m * 256 + n] = p;
        }
    }
}

// ---------------------------------------------------------------------------
// Kernel 3: MFMA flash attention — round-0 configuration (best measured:
// 47.2-47.8us; m128 tile, 16 chunks, grid 1024). attn proved insensitive to
// occupancy/barrier/staging changes across rounds 1-2; keep its best form.
// ---------------------------------------------------------------------------
#define C1F 0.09016844005556022f   // 0.0625 * log2(e)
#define LOG2EF 1.4426950408889634f

__global__ __launch_bounds__(256, 4) void attn_kernel(
    const ushort_t* __restrict__ Q, const ushort_t* __restrict__ K,
    const ushort_t* __restrict__ V, const float* __restrict__ relb,
    ushort_t* __restrict__ O)
{
    // LDS map (bytes):
    //   [0, 16384)       P: 128 rows x 128B, 16B-unit swizzle; Q staging at start
    //   [16384, 20480)   K: granule (q=s>>3)*1024 + nn*16
    //   [20480, 28672)   V dbuf: buf*4096 + s*128, 16B-unit swizzle ^(s&7)
    __shared__ __align__(16) unsigned char smem[28672];
    char* Pb = (char*)smem;
    char* Kl = (char*)(smem + 16384);
    char* Vl = (char*)(smem + 20480);

    const int blk = blockIdx.x;
    const int bh  = blk & 127;
    const int mt  = blk >> 7;
    const int b   = bh >> 3;
    const int h   = bh & 7;
    const int m0  = mt << 7;
    const int tid = threadIdx.x;
    const int w    = tid >> 6;
    const int lane = tid & 63;
    const int quad = lane >> 4;
    const int c    = lane & 15;

    const size_t base = (size_t)b * PERB + (size_t)h * 32768;
    const ushort_t* Qg = Q + base;
    const ushort_t* Kg = K + base;
    const ushort_t* Vg = V + base;
    const float* rbh = relb + h * 3969;

    // ---- stage Q [32s x 128m] into Pb (granule layout), then read frags ----
    {
        const int mm = tid & 127;
        const int sg = tid >> 7;
        union { bf16x8 v; uint16_t u[8]; } g0, g1;
#pragma unroll
        for (int j = 0; j < 8; ++j)
            g0.u[j] = Qg[(size_t)(sg * 16 + j) * 1024 + m0 + mm];
#pragma unroll
        for (int j = 0; j < 8; ++j)
            g1.u[j] = Qg[(size_t)(sg * 16 + 8 + j) * 1024 + m0 + mm];
        *(bf16x8*)(Pb + (sg * 2 + 0) * 2048 + mm * 16) = g0.v;
        *(bf16x8*)(Pb + (sg * 2 + 1) * 2048 + mm * 16) = g1.v;
    }
    __syncthreads();
    bf16x8 qfrag[8];
#pragma unroll
    for (int msub = 0; msub < 8; ++msub)
        qfrag[msub] = *(const bf16x8*)(Pb + quad * 2048 + (msub * 16 + c) * 16);

    // per-msub bias m-offset: idx = noff(n) + moff(m)
    int moff[8];
#pragma unroll
    for (int msub = 0; msub < 8; ++msub) {
        const int m = m0 + msub * 16 + c;
        moff[msub] = 1984 - (m >> 5) * 63 - (m & 31);
    }

    // accumulators
    f32x4 oacc[2][2], dacc[2];
#pragma unroll
    for (int i = 0; i < 2; ++i) {
        dacc[i] = (f32x4){0.f, 0.f, 0.f, 0.f};
#pragma unroll
        for (int j = 0; j < 2; ++j) oacc[i][j] = (f32x4){0.f, 0.f, 0.f, 0.f};
    }
    bf16x8 onesf;
#pragma unroll
    for (int j = 0; j < 8; ++j) onesf[j] = (short)0x3F80;

    // staging thread coords + hoisted LDS addresses
    const int knn = tid & 63, ksg = tid >> 6;   // K: 8 s-values for column knn
    const int vs  = tid >> 3, vng = tid & 7;    // V: unit16 vng of row vs
    const int kWr = ksg * 1024 + knn * 16;
    const int vWr = vs * 128 + ((vng ^ (vs & 7)) << 4);
    const int kRd = quad * 1024 + (w * 16 + c) * 16;
    const int pWr = c * 128 + (((2 * w + (quad >> 1)) ^ (c & 7)) << 4) + ((quad & 1) << 3);
    const int c7  = c & 7;

    // prologue: prefetch chunk 0
    uint32_t kpre[8]; bf16x8 vpre;
#pragma unroll
    for (int j = 0; j < 8; ++j) kpre[j] = Kg[(size_t)(ksg * 8 + j) * 1024 + knn];
    vpre = *(const bf16x8*)&Vg[(size_t)vs * 1024 + vng * 8];

    for (int ch = 0; ch < 16; ++ch) {
        const int n0c = ch << 6;
        const int cb  = ch & 1;

        // ---- write prefetched K/V to LDS ----
        {
            uint4 kp;
            kp.x = kpre[0] | (kpre[1] << 16);
            kp.y = kpre[2] | (kpre[3] << 16);
            kp.z = kpre[4] | (kpre[5] << 16);
            kp.w = kpre[6] | (kpre[7] << 16);
            *(uint4*)(Kl + kWr) = kp;
            *(bf16x8*)(Vl + cb * 4096 + vWr) = vpre;
        }
        __syncthreads();   // staging visible; prev PV done for all waves

        // ---- prefetch next chunk into regs (overlaps S phase) ----
        {
            const int n0n = ((ch + 1) & 15) << 6;
#pragma unroll
            for (int j = 0; j < 8; ++j)
                kpre[j] = Kg[(size_t)(ksg * 8 + j) * 1024 + n0n + knn];
            vpre = *(const bf16x8*)&Vg[(size_t)vs * 1024 + n0n + vng * 8];
        }

        // ---- S phase ----
        const bf16x8 kf = *(const bf16x8*)(Kl + kRd);
        f32x4 sacc[8];
#pragma unroll
        for (int msub = 0; msub < 8; ++msub) {
            const f32x4 z = {0.f, 0.f, 0.f, 0.f};
            sacc[msub] = __builtin_amdgcn_mfma_f32_16x16x32_bf16(kf, qfrag[msub], z, 0, 0, 0);
        }

        // ---- bias (global, L1/L2-hit) + exp2 + trunc-pack + P write ----
        const int nbase = n0c + w * 16 + quad * 4;
        const int nidx0 = (nbase >> 5) * 63 + (nbase & 31);  // 4 consecutive ints follow
#pragma unroll
        for (int msub = 0; msub < 8; ++msub) {
            const float* bp = rbh + nidx0 + moff[msub];
            float p[4];
#pragma unroll
            for (int r = 0; r < 4; ++r)
                p[r] = __builtin_amdgcn_exp2f(fmaf(bp[r], LOG2EF, sacc[msub][r] * C1F));
            uint2 pk;
            pk.x = __builtin_amdgcn_perm(__float_as_uint(p[1]), __float_as_uint(p[0]), 0x07060302u);
            pk.y = __builtin_amdgcn_perm(__float_as_uint(p[3]), __float_as_uint(p[2]), 0x07060302u);
            *(uint2*)(Pb + msub * 2048 + pWr) = pk;
        }
        __syncthreads();   // P (and V) ready for PV

        // ---- PV phase: wave w owns msub {2w, 2w+1} ----
#pragma unroll
        for (int kstep = 0; kstep < 2; ++kstep) {
            const int u = ((kstep * 4 + quad) ^ c7) << 4;
            const bf16x8 vf0 = *(const bf16x8*)(Vl + cb * 4096 + c * 128 + u);
            const bf16x8 vf1 = *(const bf16x8*)(Vl + cb * 4096 + (16 + c) * 128 + u);
#pragma unroll
            for (int mi = 0; mi < 2; ++mi) {
                const bf16x8 pf = *(const bf16x8*)(Pb + ((w * 2 + mi) * 16 + c) * 128 + u);
                oacc[0][mi] = __builtin_amdgcn_mfma_f32_16x16x32_bf16(vf0, pf, oacc[0][mi], 0, 0, 0);
                oacc[1][mi] = __builtin_amdgcn_mfma_f32_16x16x32_bf16(vf1, pf, oacc[1][mi], 0, 0, 0);
                dacc[mi]    = __builtin_amdgcn_mfma_f32_16x16x32_bf16(onesf, pf, dacc[mi], 0, 0, 0);
            }
        }
    }

    // ---- epilogue: scale by 1/denominator, write O ----
    ushort_t* Ob = O + base;
#pragma unroll
    for (int mi = 0; mi < 2; ++mi) {
        const float inv = 1.0f / dacc[mi][0];
        const int m = m0 + (w * 2 + mi) * 16 + c;
#pragma unroll
        for (int ssub = 0; ssub < 2; ++ssub)
#pragma unroll
            for (int r = 0; r < 4; ++r)
                Ob[(size_t)(ssub * 16 + quad * 4 + r) * 1024 + m] = f2bf(oacc[ssub][mi][r] * inv);
    }
}

// ---------------------------------------------------------------------------
// Kernel 4: MFMA output projection + bias + residual — same staging rebuild
// as qkv (coalesced 8-row glds, XOR-swizzled, double-buffered).
// ---------------------------------------------------------------------------
__device__ __forceinline__ void oproj_stage(
    ushort_t* Sb, const ushort_t* __restrict__ A, const ushort_t* __restrict__ wo,
    int m0, int n0, int k0, int w, int lane)
{
    const int rsub = lane >> 3;
    const int u    = lane & 7;
    const int koct = u ^ rsub;
#pragma unroll
    for (int i = 0; i < 2; ++i) {
        const int rg  = w * 2 + i;
        const int row = rg * 8 + rsub;
        const int go  = k0 + koct * 8;
        ushort_t* db = Sb + rg * 512;
        glds16(&A [(size_t)(m0 + row) * 256 + go], db);
        glds16(&wo[(size_t)(n0 + row) * 256 + go], db + 4096);
    }
}

__device__ __forceinline__ void oproj_compute(
    const ushort_t* Sb, int w, int c, int quad, f32x4 acc[4])
{
#pragma unroll
    for (int ks = 0; ks < 2; ++ks) {
        const int kq = ks * 4 + quad;
        const int uo = (kq ^ (c & 7)) * 8;
        const bf16x8 bw = *(const bf16x8*)&Sb[4096 + (w * 16 + c) * 64 + uo];
#pragma unroll
        for (int msub = 0; msub < 4; ++msub) {
            const bf16x8 af = *(const bf16x8*)&Sb[(msub * 16 + c) * 64 + uo];
            acc[msub] = __builtin_amdgcn_mfma_f32_16x16x32_bf16(bw, af, acc[msub], 0, 0, 0);
        }
    }
}

__global__ __launch_bounds__(256, 4) void oproj_kernel(
    const ushort_t* __restrict__ A, const ushort_t* __restrict__ wo,
    const float* __restrict__ bo, const float* __restrict__ x,
    float* __restrict__ out)
{
    __shared__ __align__(16) ushort_t SA0[2][4096];
    __shared__ __align__(16) ushort_t SA1[2][4096];

    const int blk = blockIdx.x;
    const int m0  = (blk >> 2) << 6;
    const int n0  = (blk & 3) << 6;
    const int tid = threadIdx.x;
    const int w    = tid >> 6;
    const int lane = tid & 63;
    const int quad = lane >> 4;
    const int c    = lane & 15;

    f32x4 acc[4];
#pragma unroll
    for (int i = 0; i < 4; ++i) acc[i] = (f32x4){0.f, 0.f, 0.f, 0.f};

    oproj_stage(&SA0[0][0], A, wo, m0, n0, 0, w, lane);
    __syncthreads();
#pragma unroll
    for (int kc = 0; kc < 4; ++kc) {
        if (kc < 3) {
            if ((kc & 1) == 0)
                oproj_stage(&SA1[0][0], A, wo, m0, n0, (kc + 1) << 6, w, lane);
            else
                oproj_stage(&SA0[0][0], A, wo, m0, n0, (kc + 1) << 6, w, lane);
        }
        if ((kc & 1) == 0) oproj_compute(&SA0[0][0], w, c, quad, acc);
        else               oproj_compute(&SA1[0][0], w, c, quad, acc);
        __syncthreads();
    }

    const int n = n0 + w * 16 + quad * 4;
    const float4 bo4 = *(const float4*)&bo[n];
#pragma unroll
    for (int msub = 0; msub < 4; ++msub) {
        const size_t g = (size_t)(m0 + msub * 16 + c) * 256 + n;
        const float4 r = *(const float4*)&x[g];
        float4 t;
        t.x = acc[msub][0] + bo4.x + r.x;
        t.y = acc[msub][1] + bo4.y + r.y;
        t.z = acc[msub][2] + bo4.z + r.z;
        t.w = acc[msub][3] + bo4.w + r.w;
        *(float4*)&out[g] = t;
    }
}

// ---------------------------------------------------------------------------
extern "C" void kernel_launch(void* const* d_in, const int* in_sizes, int n_in,
                              void* d_out, int out_size, void* d_ws, size_t ws_size,
                              hipStream_t stream)
{
    (void)in_sizes; (void)n_in; (void)out_size; (void)ws_size;
    const float* x   = (const float*)d_in[0];
    const float* lng = (const float*)d_in[1];
    const float* lnb = (const float*)d_in[2];
    const float* wq  = (const float*)d_in[3];
    const float* bq  = (const float*)d_in[4];
    const float* wk  = (const float*)d_in[5];
    const float* bk  = (const float*)d_in[6];
    const float* wv  = (const float*)d_in[7];
    const float* bv  = (const float*)d_in[8];
    const float* wo  = (const float*)d_in[9];
    const float* bo  = (const float*)d_in[10];
    const float* rb  = (const float*)d_in[11];
    // d_in[12] (rel_idx) unused: index recomputed analytically in-kernel.

    ushort_t* ws = (ushort_t*)d_ws;
    ushort_t* Xbf = ws;                       // 4194304 elems each
    ushort_t* Qbf = ws + 1 * 4194304;
    ushort_t* Kbf = ws + 2 * 4194304;
    ushort_t* Vbf = ws + 3 * 4194304;
    ushort_t* Obf = ws + 4 * 4194304;
    ushort_t* Wqb = ws + 5 * 4194304;
    ushort_t* Wkb = Wqb + 65536;
    ushort_t* Wvb = Wkb + 65536;
    ushort_t* Wob = Wvb + 65536;
    float* out = (float*)d_out;

    hipLaunchKernelGGL(prep_kernel,  dim3(768),  dim3(256), 0, stream,
                       x, lng, lnb, Xbf, wq, wk, wv, wo, Wqb, Wkb, Wvb, Wob);
    hipLaunchKernelGGL(qkv_kernel,   dim3(1024), dim3(256), 0, stream,
                       Xbf, Wqb, bq, Wkb, bk, Wvb, bv, Qbf, Kbf, Vbf);
    hipLaunchKernelGGL(attn_kernel,  dim3(1024), dim3(256), 0, stream, Qbf, Kbf, Vbf, rb, Obf);
    hipLaunchKernelGGL(oproj_kernel, dim3(1024), dim3(256), 0, stream, Obf, Wob, bo, x, out);
}